// Round 8
// baseline (229.335 us; speedup 1.0000x reference)
//
#include <hip/hip_runtime.h>
#include <hip/hip_bf16.h>
#include <math.h>

#define N 4096
#define D 128
#define NJ 4
#define KTOP 16
#define CSPLIT 4

typedef __attribute__((ext_vector_type(8))) short bf16x8;
typedef __attribute__((ext_vector_type(4))) float f32x4;

// ws layout:
//   [0, 1MB)   fh   bf16 [N][D]              normalized feature rows
//   [1MB, 5MB) gh   bf16 [NJ][N][D]          normalized negative rows
//   [5MB, 9MB) top  f32  [NJ][N][CSPLIT][16] partial sorted top-16 per col-split

// descending bitonic sort of 16 register floats (fully unrolled, branchless)
__device__ __forceinline__ void bitonic_sort16_desc(float* a) {
    #pragma unroll
    for (int k = 2; k <= 16; k <<= 1) {
        #pragma unroll
        for (int jj = k >> 1; jj > 0; jj >>= 1) {
            #pragma unroll
            for (int i = 0; i < 16; i++) {
                int l = i ^ jj;
                if (l > i) {
                    bool up = ((i & k) == 0);
                    float x = a[i], y = a[l];
                    float mx = fmaxf(x, y), mn = fminf(x, y);
                    a[i] = up ? mx : mn;
                    a[l] = up ? mn : mx;
                }
            }
        }
    }
}

// clean a bitonic 16-sequence into descending order
__device__ __forceinline__ void bitonic_clean16_desc(float* a) {
    #pragma unroll
    for (int jj = 8; jj > 0; jj >>= 1) {
        #pragma unroll
        for (int i = 0; i < 16; i++) {
            int l = i ^ jj;
            if (l > i) {
                float x = a[i], y = a[l];
                a[i] = fmaxf(x, y);
                a[l] = fminf(x, y);
            }
        }
    }
}

// ---------------- prep: fp32 L2-normalize -> bf16 (2 rows per 32-lane group) ----------------
__global__ __launch_bounds__(256) void neguni_prep(
    const float* __restrict__ feat, const float* __restrict__ negs,
    unsigned short* __restrict__ fh, unsigned short* __restrict__ gh)
{
    const int g   = threadIdx.x >> 5;
    const int l32 = threadIdx.x & 31;
    const int row = blockIdx.x * 8 + g;          // 0 .. 20479
    const float* src = (row < N) ? (feat + (size_t)row * D)
                                 : (negs + (size_t)(row - N) * D);
    unsigned short* dst = (row < N) ? (fh + (size_t)row * D)
                                    : (gh + (size_t)(row - N) * D);
    float4 v = ((const float4*)src)[l32];
    float ss = v.x * v.x + v.y * v.y + v.z * v.z + v.w * v.w;
    #pragma unroll
    for (int off = 16; off > 0; off >>= 1) ss += __shfl_xor(ss, off, 64);
    float inv = 1.0f / fmaxf(sqrtf(ss), 1e-12f);
    __hip_bfloat16 b0 = __float2bfloat16(v.x * inv);
    __hip_bfloat16 b1 = __float2bfloat16(v.y * inv);
    __hip_bfloat16 b2 = __float2bfloat16(v.z * inv);
    __hip_bfloat16 b3 = __float2bfloat16(v.w * inv);
    unsigned int lo = ((unsigned int)*(unsigned short*)&b1 << 16) | *(unsigned short*)&b0;
    unsigned int hi = ((unsigned int)*(unsigned short*)&b3 << 16) | *(unsigned short*)&b2;
    uint2 p; p.x = lo; p.y = hi;
    ((uint2*)dst)[l32] = p;
}

// ---------------- main: transposed MFMA + lane-local batched top-16 ----------------
// block: (j, 16-feature-row tile, col-split cs 0..3). wave w: 256-candidate range.
// C layout: row = candidate (quad*4+reg), col = feature (lane&15)
// -> each lane owns ONE feature row's values. grid = NJ*(N/16)*CSPLIT = 4096.
// R5 load structure (loads at chunk top, short live ranges, VGPR ~48);
// latency hiding comes from TLP: launch_bounds(256,8) + 16384 waves.
__global__ __launch_bounds__(256, 8) void neguni_main(
    const unsigned short* __restrict__ fh, const unsigned short* __restrict__ gh,
    const int* __restrict__ target, const int* __restrict__ idxp,
    float* __restrict__ topbuf)
{
    __shared__ float tops[4][16][17];

    const int tid   = threadIdx.x;
    const int w     = tid >> 6;
    const int lane  = tid & 63;
    const int col16 = lane & 15;     // feature row within tile
    const int quad  = lane >> 4;

    const int j   = blockIdx.x & 3;
    const int ft  = (blockIdx.x >> 2) & 255;
    const int cs  = blockIdx.x >> 10;           // 0..3
    const int r0  = ft * 16;
    const int c0  = cs * 1024 + w * 256;
    const int idx = idxp[0];
    const bool msk = (j == idx);

    // B fragments: 16 feature rows, persistent
    bf16x8 bfr[4];
    {
        const unsigned short* fr = fh + (size_t)(r0 + col16) * D + quad * 8;
        bfr[0] = *(const bf16x8*)(fr);
        bfr[1] = *(const bf16x8*)(fr + 32);
        bfr[2] = *(const bf16x8*)(fr + 64);
        bfr[3] = *(const bf16x8*)(fr + 96);
    }
    const int rtg = target[r0 + col16];

    float lst[KTOP];
    #pragma unroll
    for (int i = 0; i < KTOP; i++) lst[i] = -3.0e38f;

    const unsigned short* gj = gh + (size_t)j * N * D;
    const unsigned short* abase = gj + (size_t)(c0 + col16) * D + quad * 8;

    #pragma unroll 1
    for (int ch = 0; ch < 4; ch++) {
        const unsigned short* ab = abase + (size_t)(ch * 64) * D;

        f32x4 acc[4];
        #pragma unroll
        for (int t = 0; t < 4; t++) acc[t] = (f32x4){0.f, 0.f, 0.f, 0.f};

        #pragma unroll
        for (int s = 0; s < 4; s++) {
            #pragma unroll
            for (int t = 0; t < 4; t++) {
                bf16x8 a = *(const bf16x8*)(ab + t * 16 * D + s * 32);
                acc[t] = __builtin_amdgcn_mfma_f32_16x16x32_bf16(a, bfr[s], acc[t], 0, 0, 0);
            }
        }

        // gather this lane's 16 values (all for feature row r0+col16)
        const int cbase = c0 + ch * 64;
        float s16[16];
        #pragma unroll
        for (int t = 0; t < 4; t++) {
            s16[t * 4 + 0] = acc[t][0];
            s16[t * 4 + 1] = acc[t][1];
            s16[t * 4 + 2] = acc[t][2];
            s16[t * 4 + 3] = acc[t][3];
        }
        if (msk) {
            #pragma unroll
            for (int t = 0; t < 4; t++) {
                int4 tc = *(const int4*)(target + cbase + t * 16 + quad * 4);
                if (tc.x == rtg) s16[t * 4 + 0] = -1e9f;
                if (tc.y == rtg) s16[t * 4 + 1] = -1e9f;
                if (tc.z == rtg) s16[t * 4 + 2] = -1e9f;
                if (tc.w == rtg) s16[t * 4 + 3] = -1e9f;
            }
        }

        // exact top-16(lst U s16)
        bitonic_sort16_desc(s16);
        float mg[16];
        #pragma unroll
        for (int i = 0; i < 16; i++) mg[i] = fmaxf(lst[i], s16[15 - i]);
        bitonic_clean16_desc(mg);
        #pragma unroll
        for (int i = 0; i < 16; i++) lst[i] = mg[i];
    }

    // intra-wave merge across quads (lanes with same col16): 2 shfl levels
    #pragma unroll
    for (int off = 16; off <= 32; off <<= 1) {
        float mg[16];
        #pragma unroll
        for (int i = 0; i < 16; i++)
            mg[i] = fmaxf(lst[i], __shfl_xor(lst[15 - i], off, 64));
        bitonic_clean16_desc(mg);
        #pragma unroll
        for (int i = 0; i < 16; i++) lst[i] = mg[i];
    }

    if (lane < 16) {
        #pragma unroll
        for (int i = 0; i < 16; i++) tops[w][lane][i] = lst[i];
        tops[w][lane][16] = -3.0e38f;   // sentinel
    }
    __syncthreads();

    // cross-wave 4-way serial merge (waves cover disjoint candidate ranges)
    if (tid < 16) {
        int i0 = 0, i1 = 0, i2 = 0, i3 = 0;
        float* outp = topbuf + (((size_t)j * N + r0 + tid) * CSPLIT + cs) * KTOP;
        #pragma unroll
        for (int k = 0; k < KTOP; k++) {
            float v0 = tops[0][tid][i0], v1 = tops[1][tid][i1];
            float v2 = tops[2][tid][i2], v3 = tops[3][tid][i3];
            float m01 = fmaxf(v0, v1), m23 = fmaxf(v2, v3);
            float mx  = fmaxf(m01, m23);
            if      (mx == v0) i0++;
            else if (mx == v1) i1++;
            else if (mx == v2) i2++;
            else               i3++;
            outp[k] = mx;
        }
    }
}

// ---------------- finalize: 4-way merge of partials + entropy reduce ----------------
// grid = 64 blocks x 256 threads. Thread t: j = t>>6, row_l = t&63.
__global__ __launch_bounds__(256) void neguni_fin(
    const float* __restrict__ topbuf, float* __restrict__ out)
{
    __shared__ float buf[256][69];    // 4 lists of 17 (16 + sentinel) per thread
    __shared__ float mm[64][65];      // merged [row_l][k*4+j], padded
    __shared__ float red[4];

    const int t     = threadIdx.x;
    const int j     = t >> 6;
    const int row_l = t & 63;
    const int row   = blockIdx.x * 64 + row_l;

    // the 4 cs-partials of (j,row) are 64 contiguous floats
    const float4* src = (const float4*)(topbuf + ((size_t)j * N + row) * (CSPLIT * KTOP));
    #pragma unroll
    for (int q = 0; q < 16; q++) {
        float4 v = src[q];
        const int base = (q >> 2) * 17 + (q & 3) * 4;
        buf[t][base + 0] = v.x;
        buf[t][base + 1] = v.y;
        buf[t][base + 2] = v.z;
        buf[t][base + 3] = v.w;
    }
    buf[t][16] = -3.0e38f;
    buf[t][33] = -3.0e38f;
    buf[t][50] = -3.0e38f;
    buf[t][67] = -3.0e38f;

    // serial 4-way merge of the sorted (desc) lists -> global top-16
    {
        float* bp = &buf[t][0];
        int i0 = 0, i1 = 17, i2 = 34, i3 = 51;
        #pragma unroll
        for (int k = 0; k < KTOP; k++) {
            float v0 = bp[i0], v1 = bp[i1], v2 = bp[i2], v3 = bp[i3];
            float m01 = fmaxf(v0, v1);
            float m23 = fmaxf(v2, v3);
            float mx  = fmaxf(m01, m23);
            if      (mx == v0) i0++;
            else if (mx == v1) i1++;
            else if (mx == v2) i2++;
            else               i3++;
            mm[row_l][k * 4 + j] = mx;
        }
    }
    __syncthreads();

    // entropy across sets, decay-weighted; 1024 (row,k) items, 4 per thread
    float val = 0.f;
    const float Ssum = (1.0f - powf(0.95f, 16.0f)) / 0.05f;
    #pragma unroll
    for (int i = 0; i < 4; i++) {
        const int idx = t + i * 256;
        const int rl  = idx & 63;
        const int k   = idx >> 6;
        float l0 = mm[rl][k * 4 + 0] * 100.0f;
        float l1 = mm[rl][k * 4 + 1] * 100.0f;
        float l2 = mm[rl][k * 4 + 2] * 100.0f;
        float l3 = mm[rl][k * 4 + 3] * 100.0f;
        float m  = fmaxf(fmaxf(l0, l1), fmaxf(l2, l3));
        float d0 = l0 - m, d1 = l1 - m, d2 = l2 - m, d3 = l3 - m;
        float e0 = expf(d0), e1 = expf(d1), e2 = expf(d2), e3 = expf(d3);
        float s  = e0 + e1 + e2 + e3;
        float ent = (e0 * d0 + e1 * d1 + e2 * d2 + e3 * d3) / s - logf(s);
        val += ent * powf(0.95f, (float)k);
    }
    val *= 1.0f / (Ssum * (float)N);

    #pragma unroll
    for (int off = 32; off > 0; off >>= 1) val += __shfl_xor(val, off, 64);
    if ((t & 63) == 0) red[t >> 6] = val;
    __syncthreads();
    if (t == 0) atomicAdd(out, red[0] + red[1] + red[2] + red[3]);
    if (blockIdx.x == 0 && t == 0) atomicAdd(out, logf(4.0f));
}

extern "C" void kernel_launch(void* const* d_in, const int* in_sizes, int n_in,
                              void* d_out, int out_size, void* d_ws, size_t ws_size,
                              hipStream_t stream) {
    const float* feat   = (const float*)d_in[0];
    const int*   target = (const int*)d_in[1];
    const float* negs   = (const float*)d_in[2];
    const int*   idxp   = (const int*)d_in[3];
    float* out = (float*)d_out;

    unsigned short* fh = (unsigned short*)d_ws;
    unsigned short* gh = fh + (size_t)N * D;                  // +1 MB
    float* topbuf      = (float*)(gh + (size_t)NJ * N * D);   // +5 MB, 4 MB long

    hipMemsetAsync(out, 0, sizeof(float), stream);
    neguni_prep<<<dim3((N + NJ * N) / 8), dim3(256), 0, stream>>>(feat, negs, fh, gh);
    neguni_main<<<dim3(NJ * (N / 16) * CSPLIT), dim3(256), 0, stream>>>(fh, gh, target, idxp, topbuf);
    neguni_fin<<<dim3(N / 64), dim3(256), 0, stream>>>(topbuf, out);
}

// Round 9
// 219.687 us; speedup vs baseline: 1.0439x; 1.0439x over previous
//
#include <hip/hip_runtime.h>
#include <hip/hip_bf16.h>
#include <math.h>

#define N 4096
#define D 128
#define NJ 4
#define KTOP 16
#define CSPLIT 4

typedef __attribute__((ext_vector_type(8))) short bf16x8;
typedef __attribute__((ext_vector_type(4))) float f32x4;

// ws layout:
//   [0, 1MB)   fh   bf16 [N][D]              normalized feature rows
//   [1MB, 5MB) gh   bf16 [NJ][N][D]          normalized negative rows
//   [5MB, 9MB) top  f32  [NJ][N][CSPLIT][16] partial sorted top-16 per col-split

// descending bitonic sort of 16 register floats (fully unrolled, branchless)
__device__ __forceinline__ void bitonic_sort16_desc(float* a) {
    #pragma unroll
    for (int k = 2; k <= 16; k <<= 1) {
        #pragma unroll
        for (int jj = k >> 1; jj > 0; jj >>= 1) {
            #pragma unroll
            for (int i = 0; i < 16; i++) {
                int l = i ^ jj;
                if (l > i) {
                    bool up = ((i & k) == 0);
                    float x = a[i], y = a[l];
                    float mx = fmaxf(x, y), mn = fminf(x, y);
                    a[i] = up ? mx : mn;
                    a[l] = up ? mn : mx;
                }
            }
        }
    }
}

// clean a bitonic 16-sequence into descending order
__device__ __forceinline__ void bitonic_clean16_desc(float* a) {
    #pragma unroll
    for (int jj = 8; jj > 0; jj >>= 1) {
        #pragma unroll
        for (int i = 0; i < 16; i++) {
            int l = i ^ jj;
            if (l > i) {
                float x = a[i], y = a[l];
                a[i] = fmaxf(x, y);
                a[l] = fminf(x, y);
            }
        }
    }
}

// ---------------- prep: fp32 L2-normalize -> bf16 (2 rows per 32-lane group) ----------------
__global__ __launch_bounds__(256) void neguni_prep(
    const float* __restrict__ feat, const float* __restrict__ negs,
    unsigned short* __restrict__ fh, unsigned short* __restrict__ gh)
{
    const int g   = threadIdx.x >> 5;
    const int l32 = threadIdx.x & 31;
    const int row = blockIdx.x * 8 + g;          // 0 .. 20479
    const float* src = (row < N) ? (feat + (size_t)row * D)
                                 : (negs + (size_t)(row - N) * D);
    unsigned short* dst = (row < N) ? (fh + (size_t)row * D)
                                    : (gh + (size_t)(row - N) * D);
    float4 v = ((const float4*)src)[l32];
    float ss = v.x * v.x + v.y * v.y + v.z * v.z + v.w * v.w;
    #pragma unroll
    for (int off = 16; off > 0; off >>= 1) ss += __shfl_xor(ss, off, 64);
    float inv = 1.0f / fmaxf(sqrtf(ss), 1e-12f);
    __hip_bfloat16 b0 = __float2bfloat16(v.x * inv);
    __hip_bfloat16 b1 = __float2bfloat16(v.y * inv);
    __hip_bfloat16 b2 = __float2bfloat16(v.z * inv);
    __hip_bfloat16 b3 = __float2bfloat16(v.w * inv);
    unsigned int lo = ((unsigned int)*(unsigned short*)&b1 << 16) | *(unsigned short*)&b0;
    unsigned int hi = ((unsigned int)*(unsigned short*)&b3 << 16) | *(unsigned short*)&b2;
    uint2 p; p.x = lo; p.y = hi;
    ((uint2*)dst)[l32] = p;
}

// ---------------- main: transposed MFMA + lane-local batched top-16 ----------------
// block: (j, 16-feature-row tile, col-split cs 0..3). wave w: 256-candidate range.
// C layout: row = candidate (quad*4+reg), col = feature (lane&15)
// -> each lane owns ONE feature row's values. grid = NJ*(N/16)*CSPLIT = 4096.
// R5 load structure (loads at chunk top, short live ranges, VGPR ~48).
// NO launch-bounds min-waves: R8 showed forcing 8 waves/EU spills (VGPR 32,
// +24 MB scratch). 4096 blocks alone lifts occupancy (R8: 80%).
__global__ __launch_bounds__(256) void neguni_main(
    const unsigned short* __restrict__ fh, const unsigned short* __restrict__ gh,
    const int* __restrict__ target, const int* __restrict__ idxp,
    float* __restrict__ topbuf)
{
    __shared__ float tops[4][16][17];

    const int tid   = threadIdx.x;
    const int w     = tid >> 6;
    const int lane  = tid & 63;
    const int col16 = lane & 15;     // feature row within tile
    const int quad  = lane >> 4;

    const int j   = blockIdx.x & 3;
    const int ft  = (blockIdx.x >> 2) & 255;
    const int cs  = blockIdx.x >> 10;           // 0..3
    const int r0  = ft * 16;
    const int c0  = cs * 1024 + w * 256;
    const int idx = idxp[0];
    const bool msk = (j == idx);

    // B fragments: 16 feature rows, persistent
    bf16x8 bfr[4];
    {
        const unsigned short* fr = fh + (size_t)(r0 + col16) * D + quad * 8;
        bfr[0] = *(const bf16x8*)(fr);
        bfr[1] = *(const bf16x8*)(fr + 32);
        bfr[2] = *(const bf16x8*)(fr + 64);
        bfr[3] = *(const bf16x8*)(fr + 96);
    }
    const int rtg = target[r0 + col16];

    float lst[KTOP];

    const unsigned short* gj = gh + (size_t)j * N * D;
    const unsigned short* abase = gj + (size_t)(c0 + col16) * D + quad * 8;

    #pragma unroll 1
    for (int ch = 0; ch < 4; ch++) {
        const unsigned short* ab = abase + (size_t)(ch * 64) * D;

        f32x4 acc[4];
        #pragma unroll
        for (int t = 0; t < 4; t++) acc[t] = (f32x4){0.f, 0.f, 0.f, 0.f};

        #pragma unroll
        for (int s = 0; s < 4; s++) {
            #pragma unroll
            for (int t = 0; t < 4; t++) {
                bf16x8 a = *(const bf16x8*)(ab + t * 16 * D + s * 32);
                acc[t] = __builtin_amdgcn_mfma_f32_16x16x32_bf16(a, bfr[s], acc[t], 0, 0, 0);
            }
        }

        // gather this lane's 16 values (all for feature row r0+col16)
        const int cbase = c0 + ch * 64;
        float s16[16];
        #pragma unroll
        for (int t = 0; t < 4; t++) {
            s16[t * 4 + 0] = acc[t][0];
            s16[t * 4 + 1] = acc[t][1];
            s16[t * 4 + 2] = acc[t][2];
            s16[t * 4 + 3] = acc[t][3];
        }
        if (msk) {
            #pragma unroll
            for (int t = 0; t < 4; t++) {
                int4 tc = *(const int4*)(target + cbase + t * 16 + quad * 4);
                if (tc.x == rtg) s16[t * 4 + 0] = -1e9f;
                if (tc.y == rtg) s16[t * 4 + 1] = -1e9f;
                if (tc.z == rtg) s16[t * 4 + 2] = -1e9f;
                if (tc.w == rtg) s16[t * 4 + 3] = -1e9f;
            }
        }

        bitonic_sort16_desc(s16);
        if (ch == 0) {
            // first chunk: sorted incoming IS the list
            #pragma unroll
            for (int i = 0; i < 16; i++) lst[i] = s16[i];
        } else {
            float mg[16];
            #pragma unroll
            for (int i = 0; i < 16; i++) mg[i] = fmaxf(lst[i], s16[15 - i]);
            bitonic_clean16_desc(mg);
            #pragma unroll
            for (int i = 0; i < 16; i++) lst[i] = mg[i];
        }
    }

    // intra-wave merge across quads (lanes with same col16): 2 shfl levels
    #pragma unroll
    for (int off = 16; off <= 32; off <<= 1) {
        float mg[16];
        #pragma unroll
        for (int i = 0; i < 16; i++)
            mg[i] = fmaxf(lst[i], __shfl_xor(lst[15 - i], off, 64));
        bitonic_clean16_desc(mg);
        #pragma unroll
        for (int i = 0; i < 16; i++) lst[i] = mg[i];
    }

    if (lane < 16) {
        #pragma unroll
        for (int i = 0; i < 16; i++) tops[w][lane][i] = lst[i];
        tops[w][lane][16] = -3.0e38f;   // sentinel
    }
    __syncthreads();

    // cross-wave 4-way serial merge (waves cover disjoint candidate ranges)
    if (tid < 16) {
        int i0 = 0, i1 = 0, i2 = 0, i3 = 0;
        float* outp = topbuf + (((size_t)j * N + r0 + tid) * CSPLIT + cs) * KTOP;
        #pragma unroll
        for (int k = 0; k < KTOP; k++) {
            float v0 = tops[0][tid][i0], v1 = tops[1][tid][i1];
            float v2 = tops[2][tid][i2], v3 = tops[3][tid][i3];
            float m01 = fmaxf(v0, v1), m23 = fmaxf(v2, v3);
            float mx  = fmaxf(m01, m23);
            if      (mx == v0) i0++;
            else if (mx == v1) i1++;
            else if (mx == v2) i2++;
            else               i3++;
            outp[k] = mx;
        }
    }
}

// ---------------- finalize: 4-way merge of partials + entropy reduce ----------------
// grid = 64 blocks x 256 threads. Thread t: j = t>>6, row_l = t&63.
__global__ __launch_bounds__(256) void neguni_fin(
    const float* __restrict__ topbuf, float* __restrict__ out)
{
    __shared__ float buf[256][69];    // 4 lists of 17 (16 + sentinel) per thread
    __shared__ float mm[64][65];      // merged [row_l][k*4+j], padded
    __shared__ float red[4];

    const int t     = threadIdx.x;
    const int j     = t >> 6;
    const int row_l = t & 63;
    const int row   = blockIdx.x * 64 + row_l;

    // the 4 cs-partials of (j,row) are 64 contiguous floats
    const float4* src = (const float4*)(topbuf + ((size_t)j * N + row) * (CSPLIT * KTOP));
    #pragma unroll
    for (int q = 0; q < 16; q++) {
        float4 v = src[q];
        const int base = (q >> 2) * 17 + (q & 3) * 4;
        buf[t][base + 0] = v.x;
        buf[t][base + 1] = v.y;
        buf[t][base + 2] = v.z;
        buf[t][base + 3] = v.w;
    }
    buf[t][16] = -3.0e38f;
    buf[t][33] = -3.0e38f;
    buf[t][50] = -3.0e38f;
    buf[t][67] = -3.0e38f;

    // serial 4-way merge of the sorted (desc) lists -> global top-16
    {
        float* bp = &buf[t][0];
        int i0 = 0, i1 = 17, i2 = 34, i3 = 51;
        #pragma unroll
        for (int k = 0; k < KTOP; k++) {
            float v0 = bp[i0], v1 = bp[i1], v2 = bp[i2], v3 = bp[i3];
            float m01 = fmaxf(v0, v1);
            float m23 = fmaxf(v2, v3);
            float mx  = fmaxf(m01, m23);
            if      (mx == v0) i0++;
            else if (mx == v1) i1++;
            else if (mx == v2) i2++;
            else               i3++;
            mm[row_l][k * 4 + j] = mx;
        }
    }
    __syncthreads();

    // entropy across sets, decay-weighted; 1024 (row,k) items, 4 per thread
    float val = 0.f;
    const float Ssum = (1.0f - powf(0.95f, 16.0f)) / 0.05f;
    #pragma unroll
    for (int i = 0; i < 4; i++) {
        const int idx = t + i * 256;
        const int rl  = idx & 63;
        const int k   = idx >> 6;
        float l0 = mm[rl][k * 4 + 0] * 100.0f;
        float l1 = mm[rl][k * 4 + 1] * 100.0f;
        float l2 = mm[rl][k * 4 + 2] * 100.0f;
        float l3 = mm[rl][k * 4 + 3] * 100.0f;
        float m  = fmaxf(fmaxf(l0, l1), fmaxf(l2, l3));
        float d0 = l0 - m, d1 = l1 - m, d2 = l2 - m, d3 = l3 - m;
        float e0 = expf(d0), e1 = expf(d1), e2 = expf(d2), e3 = expf(d3);
        float s  = e0 + e1 + e2 + e3;
        float ent = (e0 * d0 + e1 * d1 + e2 * d2 + e3 * d3) / s - logf(s);
        val += ent * powf(0.95f, (float)k);
    }
    val *= 1.0f / (Ssum * (float)N);

    #pragma unroll
    for (int off = 32; off > 0; off >>= 1) val += __shfl_xor(val, off, 64);
    if ((t & 63) == 0) red[t >> 6] = val;
    __syncthreads();
    if (t == 0) atomicAdd(out, red[0] + red[1] + red[2] + red[3]);
    if (blockIdx.x == 0 && t == 0) atomicAdd(out, logf(4.0f));
}

extern "C" void kernel_launch(void* const* d_in, const int* in_sizes, int n_in,
                              void* d_out, int out_size, void* d_ws, size_t ws_size,
                              hipStream_t stream) {
    const float* feat   = (const float*)d_in[0];
    const int*   target = (const int*)d_in[1];
    const float* negs   = (const float*)d_in[2];
    const int*   idxp   = (const int*)d_in[3];
    float* out = (float*)d_out;

    unsigned short* fh = (unsigned short*)d_ws;
    unsigned short* gh = fh + (size_t)N * D;                  // +1 MB
    float* topbuf      = (float*)(gh + (size_t)NJ * N * D);   // +5 MB, 4 MB long

    hipMemsetAsync(out, 0, sizeof(float), stream);
    neguni_prep<<<dim3((N + NJ * N) / 8), dim3(256), 0, stream>>>(feat, negs, fh, gh);
    neguni_main<<<dim3(NJ * (N / 16) * CSPLIT), dim3(256), 0, stream>>>(fh, gh, target, idxp, topbuf);
    neguni_fin<<<dim3(N / 64), dim3(256), 0, stream>>>(topbuf, out);
}

// Round 10
// 133.837 us; speedup vs baseline: 1.7135x; 1.6415x over previous
//
#include <hip/hip_runtime.h>
#include <hip/hip_bf16.h>
#include <math.h>

#define N 4096
#define D 128
#define NJ 4
#define KTOP 16
#define CSPLIT 2

typedef __attribute__((ext_vector_type(8))) short bf16x8;
typedef __attribute__((ext_vector_type(4))) float f32x4;

// ws layout:
//   [0, 1MB)   fh   bf16 [N][D]       normalized feature rows, row-major
//   [1MB, 5MB) gh   bf16 [NJ][N*D]    normalized negative rows, FRAGMENT-MAJOR:
//              per j, per 64-cand chunk chg (64 chunks): 16 frags x 512 ushorts.
//              frag (s,t) holds lane l's 16B at (chg*8192 + (s*4+t)*512 + l*8).
//              Lane l=quad*16+col16 <-> cand = t*16+col16, bytes [s*64+quad*16).
//              => every A-load in main is base + lane*16: perfectly coalesced.
//   [5MB, 7MB) top  f32  [NJ][N][CSPLIT][16] partial sorted top-16 per col-split

// descending bitonic sort of 16 register floats (fully unrolled, branchless)
__device__ __forceinline__ void bitonic_sort16_desc(float* a) {
    #pragma unroll
    for (int k = 2; k <= 16; k <<= 1) {
        #pragma unroll
        for (int jj = k >> 1; jj > 0; jj >>= 1) {
            #pragma unroll
            for (int i = 0; i < 16; i++) {
                int l = i ^ jj;
                if (l > i) {
                    bool up = ((i & k) == 0);
                    float x = a[i], y = a[l];
                    float mx = fmaxf(x, y), mn = fminf(x, y);
                    a[i] = up ? mx : mn;
                    a[l] = up ? mn : mx;
                }
            }
        }
    }
}

// clean a bitonic 16-sequence into descending order
__device__ __forceinline__ void bitonic_clean16_desc(float* a) {
    #pragma unroll
    for (int jj = 8; jj > 0; jj >>= 1) {
        #pragma unroll
        for (int i = 0; i < 16; i++) {
            int l = i ^ jj;
            if (l > i) {
                float x = a[i], y = a[l];
                a[i] = fmaxf(x, y);
                a[l] = fminf(x, y);
            }
        }
    }
}

// ---------------- prep: fp32 L2-normalize -> bf16, negs to fragment-major ----------------
// 16 lanes per row (lane p = 16B piece), 4 rows per wave, 16 rows per block.
__global__ __launch_bounds__(256) void neguni_prep(
    const float* __restrict__ feat, const float* __restrict__ negs,
    unsigned short* __restrict__ fh, unsigned short* __restrict__ gh)
{
    const int w    = threadIdx.x >> 6;
    const int lane = threadIdx.x & 63;
    const int p    = lane & 15;                    // piece 0..15
    const int rr   = lane >> 4;                    // row within wave
    const int row  = blockIdx.x * 16 + w * 4 + rr; // 0..20479

    const float* src = (row < N) ? (feat + (size_t)row * D)
                                 : (negs + (size_t)(row - N) * D);
    float4 v0 = ((const float4*)src)[p * 2];
    float4 v1 = ((const float4*)src)[p * 2 + 1];
    float ss = v0.x*v0.x + v0.y*v0.y + v0.z*v0.z + v0.w*v0.w
             + v1.x*v1.x + v1.y*v1.y + v1.z*v1.z + v1.w*v1.w;
    ss += __shfl_xor(ss, 1, 64);
    ss += __shfl_xor(ss, 2, 64);
    ss += __shfl_xor(ss, 4, 64);
    ss += __shfl_xor(ss, 8, 64);
    const float inv = 1.0f / fmaxf(sqrtf(ss), 1e-12f);

    float f[8] = {v0.x, v0.y, v0.z, v0.w, v1.x, v1.y, v1.z, v1.w};
    unsigned int u[4];
    #pragma unroll
    for (int i = 0; i < 4; i++) {
        __hip_bfloat16 b0 = __float2bfloat16(f[2*i]   * inv);
        __hip_bfloat16 b1 = __float2bfloat16(f[2*i+1] * inv);
        u[i] = ((unsigned int)*(unsigned short*)&b1 << 16) | *(unsigned short*)&b0;
    }
    uint4 pk; pk.x = u[0]; pk.y = u[1]; pk.z = u[2]; pk.w = u[3];

    if (row < N) {
        *(uint4*)(fh + (size_t)row * D + p * 8) = pk;          // row-major
    } else {
        const int rn  = row - N;
        const int j   = rn >> 12;
        const int rj  = rn & 4095;
        const int chg = rj >> 6;       // 64-cand chunk
        const int cl  = rj & 63;
        const int t   = cl >> 4;
        const int col = cl & 15;
        const int s   = p >> 2;
        const int q   = p & 3;
        *(uint4*)(gh + (size_t)j * N * D + (size_t)chg * 8192
                  + (s * 4 + t) * 512 + (q * 16 + col) * 8) = pk;
    }
}

// ---------------- main: transposed MFMA + lane-local batched top-16 ----------------
// block: (j, 16-feature-row tile, col-split). wave w: 512-candidate range.
// C layout: row = candidate (quad*4+reg), col = feature (lane&15)
// -> each lane owns ONE feature row's values. grid = NJ*(N/16)*CSPLIT = 2048.
// A-loads are fragment-major: each load reads base+lane*16 (contiguous 1KB).
__global__ __launch_bounds__(256) void neguni_main(
    const unsigned short* __restrict__ fh, const unsigned short* __restrict__ gh,
    const int* __restrict__ target, const int* __restrict__ idxp,
    float* __restrict__ topbuf)
{
    __shared__ float tops[4][16][17];

    const int tid   = threadIdx.x;
    const int w     = tid >> 6;
    const int lane  = tid & 63;
    const int col16 = lane & 15;     // feature row within tile
    const int quad  = lane >> 4;

    const int j   = blockIdx.x & 3;
    const int ft  = (blockIdx.x >> 2) & 255;
    const int cs  = blockIdx.x >> 10;
    const int r0  = ft * 16;
    const int c0  = cs * 2048 + w * 512;
    const int idx = idxp[0];
    const bool msk = (j == idx);

    // B fragments: 16 feature rows, persistent (row-major fh, one-time scatter)
    bf16x8 bfr[4];
    {
        const unsigned short* fr = fh + (size_t)(r0 + col16) * D + quad * 8;
        bfr[0] = *(const bf16x8*)(fr);
        bfr[1] = *(const bf16x8*)(fr + 32);
        bfr[2] = *(const bf16x8*)(fr + 64);
        bfr[3] = *(const bf16x8*)(fr + 96);
    }
    const int rtg = target[r0 + col16];

    float lst[KTOP];

    // fragment-major A base for this wave's first chunk
    const int chg0 = cs * 32 + w * 8;
    const unsigned short* ab0 = gh + (size_t)j * N * D + (size_t)chg0 * 8192 + lane * 8;

    #pragma unroll 1
    for (int ch = 0; ch < 8; ch++) {
        const unsigned short* ab = ab0 + (size_t)ch * 8192;

        f32x4 acc[4];
        #pragma unroll
        for (int t = 0; t < 4; t++) acc[t] = (f32x4){0.f, 0.f, 0.f, 0.f};

        #pragma unroll
        for (int s = 0; s < 4; s++) {
            #pragma unroll
            for (int t = 0; t < 4; t++) {
                bf16x8 a = *(const bf16x8*)(ab + (s * 4 + t) * 512);
                acc[t] = __builtin_amdgcn_mfma_f32_16x16x32_bf16(a, bfr[s], acc[t], 0, 0, 0);
            }
        }

        // gather this lane's 16 values (all for feature row r0+col16)
        const int cbase = c0 + ch * 64;
        float s16[16];
        #pragma unroll
        for (int t = 0; t < 4; t++) {
            s16[t * 4 + 0] = acc[t][0];
            s16[t * 4 + 1] = acc[t][1];
            s16[t * 4 + 2] = acc[t][2];
            s16[t * 4 + 3] = acc[t][3];
        }
        if (msk) {
            #pragma unroll
            for (int t = 0; t < 4; t++) {
                int4 tc = *(const int4*)(target + cbase + t * 16 + quad * 4);
                if (tc.x == rtg) s16[t * 4 + 0] = -1e9f;
                if (tc.y == rtg) s16[t * 4 + 1] = -1e9f;
                if (tc.z == rtg) s16[t * 4 + 2] = -1e9f;
                if (tc.w == rtg) s16[t * 4 + 3] = -1e9f;
            }
        }

        bitonic_sort16_desc(s16);
        if (ch == 0) {
            #pragma unroll
            for (int i = 0; i < 16; i++) lst[i] = s16[i];
        } else {
            float mg[16];
            #pragma unroll
            for (int i = 0; i < 16; i++) mg[i] = fmaxf(lst[i], s16[15 - i]);
            bitonic_clean16_desc(mg);
            #pragma unroll
            for (int i = 0; i < 16; i++) lst[i] = mg[i];
        }
    }

    // intra-wave merge across quads (lanes with same col16): 2 shfl levels
    #pragma unroll
    for (int off = 16; off <= 32; off <<= 1) {
        float mg[16];
        #pragma unroll
        for (int i = 0; i < 16; i++)
            mg[i] = fmaxf(lst[i], __shfl_xor(lst[15 - i], off, 64));
        bitonic_clean16_desc(mg);
        #pragma unroll
        for (int i = 0; i < 16; i++) lst[i] = mg[i];
    }

    if (lane < 16) {
        #pragma unroll
        for (int i = 0; i < 16; i++) tops[w][lane][i] = lst[i];
        tops[w][lane][16] = -3.0e38f;   // sentinel
    }
    __syncthreads();

    // cross-wave 4-way serial merge (waves cover disjoint candidate ranges)
    if (tid < 16) {
        int i0 = 0, i1 = 0, i2 = 0, i3 = 0;
        float* outp = topbuf + (((size_t)j * N + r0 + tid) * CSPLIT + cs) * KTOP;
        #pragma unroll
        for (int k = 0; k < KTOP; k++) {
            float v0 = tops[0][tid][i0], v1 = tops[1][tid][i1];
            float v2 = tops[2][tid][i2], v3 = tops[3][tid][i3];
            float m01 = fmaxf(v0, v1), m23 = fmaxf(v2, v3);
            float mx  = fmaxf(m01, m23);
            if      (mx == v0) i0++;
            else if (mx == v1) i1++;
            else if (mx == v2) i2++;
            else               i3++;
            outp[k] = mx;
        }
    }
}

// ---------------- finalize: 2-way merge of partials + entropy reduce ----------------
__global__ __launch_bounds__(256) void neguni_fin(
    const float* __restrict__ topbuf, float* __restrict__ out)
{
    __shared__ float buf[256][35];    // 2 lists of 17 (16 + sentinel) per thread
    __shared__ float mm[64][65];      // merged [row_l][k*4+j], padded
    __shared__ float red[4];

    const int t     = threadIdx.x;
    const int j     = t >> 6;
    const int row_l = t & 63;
    const int row   = blockIdx.x * 64 + row_l;

    const float4* src = (const float4*)(topbuf + ((size_t)j * N + row) * (CSPLIT * KTOP));
    #pragma unroll
    for (int q = 0; q < 8; q++) {
        float4 v = src[q];
        const int base = (q >> 2) * 17 + (q & 3) * 4;
        buf[t][base + 0] = v.x;
        buf[t][base + 1] = v.y;
        buf[t][base + 2] = v.z;
        buf[t][base + 3] = v.w;
    }
    buf[t][16] = -3.0e38f;
    buf[t][33] = -3.0e38f;

    {
        int ia = 0, ib = 17;
        #pragma unroll
        for (int k = 0; k < KTOP; k++) {
            float va = buf[t][ia], vb = buf[t][ib];
            bool ta = va >= vb;
            mm[row_l][k * 4 + j] = ta ? va : vb;
            if (ta) ia++; else ib++;
        }
    }
    __syncthreads();

    float val = 0.f;
    const float Ssum = (1.0f - powf(0.95f, 16.0f)) / 0.05f;
    #pragma unroll
    for (int i = 0; i < 4; i++) {
        const int idx = t + i * 256;
        const int rl  = idx & 63;
        const int k   = idx >> 6;
        float l0 = mm[rl][k * 4 + 0] * 100.0f;
        float l1 = mm[rl][k * 4 + 1] * 100.0f;
        float l2 = mm[rl][k * 4 + 2] * 100.0f;
        float l3 = mm[rl][k * 4 + 3] * 100.0f;
        float m  = fmaxf(fmaxf(l0, l1), fmaxf(l2, l3));
        float d0 = l0 - m, d1 = l1 - m, d2 = l2 - m, d3 = l3 - m;
        float e0 = expf(d0), e1 = expf(d1), e2 = expf(d2), e3 = expf(d3);
        float s  = e0 + e1 + e2 + e3;
        float ent = (e0 * d0 + e1 * d1 + e2 * d2 + e3 * d3) / s - logf(s);
        val += ent * powf(0.95f, (float)k);
    }
    val *= 1.0f / (Ssum * (float)N);

    #pragma unroll
    for (int off = 32; off > 0; off >>= 1) val += __shfl_xor(val, off, 64);
    if ((t & 63) == 0) red[t >> 6] = val;
    __syncthreads();
    if (t == 0) atomicAdd(out, red[0] + red[1] + red[2] + red[3]);
    if (blockIdx.x == 0 && t == 0) atomicAdd(out, logf(4.0f));
}

extern "C" void kernel_launch(void* const* d_in, const int* in_sizes, int n_in,
                              void* d_out, int out_size, void* d_ws, size_t ws_size,
                              hipStream_t stream) {
    const float* feat   = (const float*)d_in[0];
    const int*   target = (const int*)d_in[1];
    const float* negs   = (const float*)d_in[2];
    const int*   idxp   = (const int*)d_in[3];
    float* out = (float*)d_out;

    unsigned short* fh = (unsigned short*)d_ws;
    unsigned short* gh = fh + (size_t)N * D;                  // +1 MB
    float* topbuf      = (float*)(gh + (size_t)NJ * N * D);   // +5 MB, 2 MB long

    hipMemsetAsync(out, 0, sizeof(float), stream);
    neguni_prep<<<dim3((N + NJ * N) / 16), dim3(256), 0, stream>>>(feat, negs, fh, gh);
    neguni_main<<<dim3(NJ * (N / 16) * CSPLIT), dim3(256), 0, stream>>>(fh, gh, target, idxp, topbuf);
    neguni_fin<<<dim3(N / 64), dim3(256), 0, stream>>>(topbuf, out);
}